// Round 8
// baseline (240.479 us; speedup 1.0000x reference)
//
#include <hip/hip_runtime.h>
#include <hip/hip_bf16.h>
#include <stdint.h>

#define B_ 2
#define S_ 2048
#define D_ 1024
#define H_ 16
#define DK_ 64

typedef __attribute__((ext_vector_type(4))) float floatx4;
typedef __attribute__((ext_vector_type(8))) short shortx8;
typedef __attribute__((ext_vector_type(4))) short shortx4;
typedef unsigned short ushort_t;

// f32 -> bf16 round-to-nearest-even (used for GEMM outputs)
__device__ inline ushort_t f2bf(float f) {
  union { float f; unsigned u; } v; v.f = f;
  unsigned r = v.u + 0x7FFFu + ((v.u >> 16) & 1u);
  return (ushort_t)(r >> 16);
}

// pack two f32 -> bf16x2, round-to-nearest-even (for in-GEMM A conversion)
__device__ inline unsigned pk_rne(float a, float b) {
  unsigned ua = __float_as_uint(a), ub = __float_as_uint(b);
  ua += 0x7FFFu + ((ua >> 16) & 1u);
  ub += 0x7FFFu + ((ub >> 16) & 1u);
  return __builtin_amdgcn_perm(ub, ua, 0x07060302u);
}

// pack two f32 -> bf16x2 by truncation (1 v_perm); fine for P >= 0 / O
__device__ inline unsigned pack2bf(float lo, float hi) {
  return __builtin_amdgcn_perm(__float_as_uint(hi), __float_as_uint(lo), 0x07060302u);
}

__device__ inline shortx4 mk_sx4(unsigned lo, unsigned hi) {
  union { unsigned u[2]; shortx4 s; } v; v.u[0] = lo; v.u[1] = hi; return v.s;
}

__device__ inline float fast_exp2(float x) {
#if __has_builtin(__builtin_amdgcn_exp2f)
  return __builtin_amdgcn_exp2f(x);
#else
  return __expf(0.69314718056f * x);
#endif
}

__device__ inline void gload_lds16(const void* g, void* l) {
  __builtin_amdgcn_global_load_lds(
      (const __attribute__((address_space(1))) unsigned int*)g,
      (__attribute__((address_space(3))) unsigned int*)l, 16, 0, 0);
}

__device__ inline floatx4 mfma16x16x16bf16(shortx4 a, shortx4 b, floatx4 c) {
#if __has_builtin(__builtin_amdgcn_mfma_f32_16x16x16bf16_1k)
  return __builtin_amdgcn_mfma_f32_16x16x16bf16_1k(a, b, c, 0, 0, 0);
#else
  floatx4 d;
  asm("v_mfma_f32_16x16x16_bf16 %0, %1, %2, %3" : "=v"(d) : "v"(a), "v"(b), "v"(c));
  return d;
#endif
}

// ---------------- fp32 -> bf16 conversion (4 weight tensors only) ----------
// Activation conversion is fused into the QKV GEMM's A-staging (round 8):
// the standalone kernel was 144 MB of pure BW (~23 us) + a launch gap.
struct ConvWArgs {
  const float* src[4];
  ushort_t* dst[4];
};

__global__ __launch_bounds__(256) void convert_w_kernel(ConvWArgs a) {
  int seg = blockIdx.x >> 8, bis = blockIdx.x & 255;
  const float4* src = (const float4*)(a.src[seg]) + (size_t)bis * 1024;
  ushort4* dst = (ushort4*)(a.dst[seg]) + (size_t)bis * 1024;
#pragma unroll
  for (int i = 0; i < 4; ++i) {
    int idx = i * 256 + threadIdx.x;
    float4 v = src[idx];
    ushort4 o;
    o.x = f2bf(v.x); o.y = f2bf(v.y); o.z = f2bf(v.z); o.w = f2bf(v.w);
    dst[idx] = o;
  }
}

struct QkvArgs {
  const float* Af[3];   // fp32 activations straight from d_in
  const ushort_t* W[3];
  const float* bias[3];
  ushort_t* out[3];
  float scale[3];
};

// ---------------- QKV GEMM with fused A-conversion -------------------------
// 128x128 tile, BK=32, double-buffered LDS. W staged async (global_load_lds,
// bf16); A staged fp32 global -> VGPR -> RNE pack -> ds_write_b128 (numerics
// identical to the old standalone convert). Per-XCD L2 working set: 2 MB
// A-fp32 stripe + 2 MB W-bf16 = 4 MB (fits; W in fp32 would blow it).
// z==2 (V) writes the transposed layout consumed by attention.
__global__ __launch_bounds__(256, 3) void gemm_qkv_kernel(QkvArgs a) {
  const int z = blockIdx.z;
  const int m0 = (blockIdx.x * 4 + (blockIdx.y >> 3)) * 128;
  const int n0 = (blockIdx.y & 7) * 128;
  const float* __restrict__ A = a.Af[z];
  const ushort_t* __restrict__ W = a.W[z];
  const float* __restrict__ bias = a.bias[z];
  const float scl = a.scale[z];
  ushort_t* __restrict__ outp = a.out[z];
  const int outmode = (z == 2) ? 2 : 0;
  constexpr int K = D_;

  __shared__ ushort_t smem[2][8192];  // per buf: A[128][32] | W[128][32] bf16
  const int tid = threadIdx.x;
  const int wave = tid >> 6;
  const int lane = tid & 63;
  const int quad = lane >> 4;
  const int l16 = lane & 15;
  const int wm = (wave >> 1) * 64;
  const int wn = (wave & 1) * 64;

  floatx4 acc[4][4] = {};

  // W async staging: wave w covers rows [w*32, w*32+32) via 2 gloads
  const ushort_t* wsrc[2];
  int wdst[2];
#pragma unroll
  for (int g = 0; g < 2; ++g) {
    int gg = wave * 2 + g;
    wsrc[g] = W + (size_t)(n0 + gg * 16 + (lane >> 2)) * K + (lane & 3) * 8;
    wdst[g] = 4096 + gg * 512;
  }
  // A staging: 512 16B-chunks; lane owns chunks tid and 256+tid.
  // chunk c: row=c>>2, kc=c&3 -> LDS ushort offset c*8; fp32 src 2x float4.
  const float* asrc0 = A + (size_t)(m0 + (tid >> 2)) * K + (tid & 3) * 8;
  const float* asrc1 = A + (size_t)(m0 + 64 + (tid >> 2)) * K + (tid & 3) * 8;
  const int adst0 = tid * 8;
  const int adst1 = 2048 + tid * 8;

  // prologue: stage tile 0 into buffer 0
#pragma unroll
  for (int g = 0; g < 2; ++g) gload_lds16(wsrc[g], &smem[0][wdst[g]]);
  {
    float4 a0 = *(const float4*)(asrc0);
    float4 a1 = *(const float4*)(asrc0 + 4);
    float4 a2 = *(const float4*)(asrc1);
    float4 a3 = *(const float4*)(asrc1 + 4);
    uint4 p0, p1;
    p0.x = pk_rne(a0.x, a0.y); p0.y = pk_rne(a0.z, a0.w);
    p0.z = pk_rne(a1.x, a1.y); p0.w = pk_rne(a1.z, a1.w);
    p1.x = pk_rne(a2.x, a2.y); p1.y = pk_rne(a2.z, a2.w);
    p1.z = pk_rne(a3.x, a3.y); p1.w = pk_rne(a3.z, a3.w);
    *(uint4*)(&smem[0][adst0]) = p0;
    *(uint4*)(&smem[0][adst1]) = p1;
  }

  for (int j = 0; j < 32; ++j) {
    __syncthreads();
    float4 a0, a1, a2, a3;
    const bool pre = (j + 1 < 32);
    if (pre) {
      const int ko = (j + 1) * 32;
      ushort_t* bufn = smem[(j + 1) & 1];
#pragma unroll
      for (int g = 0; g < 2; ++g) gload_lds16(wsrc[g] + ko, bufn + wdst[g]);
      a0 = *(const float4*)(asrc0 + ko);
      a1 = *(const float4*)(asrc0 + ko + 4);
      a2 = *(const float4*)(asrc1 + ko);
      a3 = *(const float4*)(asrc1 + ko + 4);
    }
    const ushort_t* aT = smem[j & 1];
    const ushort_t* bT = smem[j & 1] + 4096;
    shortx8 af[4], bf[4];
#pragma unroll
    for (int mi = 0; mi < 4; ++mi)
      af[mi] = *(const shortx8*)(aT + (wm + mi * 16 + l16) * 32 + quad * 8);
#pragma unroll
    for (int ni = 0; ni < 4; ++ni)
      bf[ni] = *(const shortx8*)(bT + (wn + ni * 16 + l16) * 32 + quad * 8);
#pragma unroll
    for (int mi = 0; mi < 4; ++mi)
#pragma unroll
      for (int ni = 0; ni < 4; ++ni)
        acc[mi][ni] = __builtin_amdgcn_mfma_f32_16x16x32_bf16(af[mi], bf[ni], acc[mi][ni], 0, 0, 0);
    if (pre) {
      ushort_t* bufn = smem[(j + 1) & 1];
      uint4 p0, p1;
      p0.x = pk_rne(a0.x, a0.y); p0.y = pk_rne(a0.z, a0.w);
      p0.z = pk_rne(a1.x, a1.y); p0.w = pk_rne(a1.z, a1.w);
      p1.x = pk_rne(a2.x, a2.y); p1.y = pk_rne(a2.z, a2.w);
      p1.z = pk_rne(a3.x, a3.y); p1.w = pk_rne(a3.z, a3.w);
      *(uint4*)(bufn + adst0) = p0;
      *(uint4*)(bufn + adst1) = p1;
    }
  }

  // epilogue: C/D layout col=lane&15, row=quad*4+r
#pragma unroll
  for (int ni = 0; ni < 4; ++ni) {
    int n = n0 + wn + ni * 16 + l16;
    float bv = bias[n];
#pragma unroll
    for (int mi = 0; mi < 4; ++mi) {
      if (outmode == 2) {
        int m = m0 + wm + mi * 16 + quad * 4;
        int b = m >> 11, s = m & 2047;
        ushort_t* dst = outp + (((size_t)(b * 1024 + n)) << 11) + s;
        uint2 pk;
        pk.x = (unsigned)f2bf(acc[mi][ni][0] + bv) |
               ((unsigned)f2bf(acc[mi][ni][1] + bv) << 16);
        pk.y = (unsigned)f2bf(acc[mi][ni][2] + bv) |
               ((unsigned)f2bf(acc[mi][ni][3] + bv) << 16);
        *(uint2*)(dst) = pk;  // single 8B store (8B-aligned: s = quad*4)
      } else {
#pragma unroll
        for (int r = 0; r < 4; ++r) {
          int m = m0 + wm + mi * 16 + quad * 4 + r;
          outp[(size_t)m * D_ + n] = f2bf((acc[mi][ni][r] + bv) * scl);
        }
      }
    }
  }
}

// ---------------- out-proj GEMM (bf16 A via async staging, f32 out) --------
// 64x128 tile, BK=32, double-buffered; grid (8,64) = 512 blocks = 2/CU.
__global__ __launch_bounds__(256) void gemm_out_kernel(const ushort_t* __restrict__ A,
                                                       const ushort_t* __restrict__ W,
                                                       const float* __restrict__ bias,
                                                       float* __restrict__ out) {
  const int m0 = (blockIdx.x * 8 + (blockIdx.y >> 3)) * 64;
  const int n0 = (blockIdx.y & 7) * 128;
  constexpr int K = D_;
  __shared__ ushort_t smem[2][6144];  // per buf: A[64][32] | W[128][32]
  const int tid = threadIdx.x;
  const int wave = tid >> 6;
  const int lane = tid & 63;
  const int quad = lane >> 4;
  const int l16 = lane & 15;
  const int wm = (wave >> 1) * 32;
  const int wn = (wave & 1) * 64;

  floatx4 acc[2][4] = {};

  const ushort_t* gsrc[3];
  int ldst[3];
#pragma unroll
  for (int i = 0; i < 3; ++i) {
    int g = wave * 3 + i;
    int row = lane >> 2;
    int col = (lane & 3) * 8;
    if (g < 4) {
      gsrc[i] = A + (size_t)(m0 + g * 16 + row) * K + col;
      ldst[i] = g * 512;
    } else {
      gsrc[i] = W + (size_t)(n0 + (g - 4) * 16 + row) * K + col;
      ldst[i] = 2048 + (g - 4) * 512;
    }
  }

#pragma unroll
  for (int i = 0; i < 3; ++i) gload_lds16(gsrc[i], &smem[0][ldst[i]]);

  for (int j = 0; j < 32; ++j) {
    __syncthreads();
    if (j + 1 < 32) {
      const int ko = (j + 1) * 32;
      ushort_t* bufn = smem[(j + 1) & 1];
#pragma unroll
      for (int i = 0; i < 3; ++i) gload_lds16(gsrc[i] + ko, bufn + ldst[i]);
    }
    const ushort_t* aT = smem[j & 1];
    const ushort_t* bT = smem[j & 1] + 2048;
    shortx8 af[2], bf[4];
#pragma unroll
    for (int mi = 0; mi < 2; ++mi)
      af[mi] = *(const shortx8*)(aT + (wm + mi * 16 + l16) * 32 + quad * 8);
#pragma unroll
    for (int ni = 0; ni < 4; ++ni)
      bf[ni] = *(const shortx8*)(bT + (wn + ni * 16 + l16) * 32 + quad * 8);
#pragma unroll
    for (int mi = 0; mi < 2; ++mi)
#pragma unroll
      for (int ni = 0; ni < 4; ++ni)
        acc[mi][ni] = __builtin_amdgcn_mfma_f32_16x16x32_bf16(af[mi], bf[ni], acc[mi][ni], 0, 0, 0);
  }

#pragma unroll
  for (int ni = 0; ni < 4; ++ni) {
    int n = n0 + wn + ni * 16 + l16;
    float bv = bias[n];
#pragma unroll
    for (int mi = 0; mi < 2; ++mi)
#pragma unroll
      for (int r = 0; r < 4; ++r) {
        int m = m0 + wm + mi * 16 + quad * 4 + r;
        out[(size_t)m * D_ + n] = acc[mi][ni][r] + bv;
      }
  }
}

// ---------------- flash attention (causal), pipelined, no-max softmax ------
// 1D grid of 512; id<256 -> (b=0, qt=15-(id>>4)), id>=256 -> (b=1, qt=id>>4).
// With round-robin block->CU dispatch, CU c gets blocks c and c+256 whose
// iteration counts sum to a CONSTANT 36 -> balanced makespan.
__global__ __launch_bounds__(256, 2) void attn_kernel(const ushort_t* __restrict__ Qp,
                                                      const ushort_t* __restrict__ Kp,
                                                      const ushort_t* __restrict__ Vt,
                                                      ushort_t* __restrict__ O) {
  const int id = blockIdx.x;
  const int h = id & 15;
  const int qq = (id & 255) >> 4;
  const int b = id >> 8;
  const int qt = b ? qq : 15 - qq;
  const int q0 = qt * 128;
  const int tid = threadIdx.x;
  const int wave = tid >> 6;
  const int lane = tid & 63;
  const int quad = lane >> 4;
  const int l16 = lane & 15;

  __shared__ ushort_t smem[2][8192];  // per buf: k tile [64][64] | v^T tile [64][64]

  const size_t hoff = (size_t)h * DK_;

  // Q B-frags: lane holds Q[q=l16][d=ks*32+quad*8+i] (already exp2-scaled)
  shortx8 qf[2][2];
#pragma unroll
  for (int grp = 0; grp < 2; ++grp) {
    const ushort_t* qrow = Qp + ((size_t)b * S_ + q0 + wave * 32 + grp * 16 + l16) * D_ + hoff;
#pragma unroll
    for (int ks = 0; ks < 2; ++ks)
      qf[grp][ks] = *(const shortx8*)(qrow + ks * 32 + quad * 8);
  }

  // staging: wave w stages K rows [w*16,+16) and V^T rows [w*16,+16)
  const int r8 = lane >> 3;               // row within 8-row chunk
  const int jj8 = ((lane & 7) ^ r8) * 8;  // swizzled 16B chunk, ushort units
  const ushort_t* kb[2];
  const ushort_t* vb[2];
#pragma unroll
  for (int g = 0; g < 2; ++g) {
    int r = wave * 16 + g * 8 + r8;
    kb[g] = Kp + ((size_t)b * S_ + r) * D_ + hoff + jj8;
    vb[g] = Vt + ((size_t)(b * H_ + h) * 64 + r) * S_ + jj8;
  }
  const int ldsrow = (wave * 16) * 64;

  floatx4 oacc[2][4] = {};
  float l_run[2] = {0.f, 0.f};
  const int nj = 2 * qt + 2;
  const int qwave_max = q0 + wave * 32 + 31;

  // preload tile 0 into buffer 0
#pragma unroll
  for (int g = 0; g < 2; ++g) {
    gload_lds16(kb[g], &smem[0][ldsrow + g * 512]);
    gload_lds16(vb[g], &smem[0][4096 + ldsrow + g * 512]);
  }

  for (int j = 0; j < nj; ++j) {
    __syncthreads();
    if (j + 1 < nj) {
      ushort_t* bufn = smem[(j + 1) & 1];
      const size_t ko = (size_t)(j + 1) * 64 * D_;
      const int vo = (j + 1) * 64;
#pragma unroll
      for (int g = 0; g < 2; ++g) {
        gload_lds16(kb[g] + ko, bufn + ldsrow + g * 512);
        gload_lds16(vb[g] + vo, bufn + 4096 + ldsrow + g * 512);
      }
    }
    if ((j << 6) > qwave_max) continue;  // tile fully masked for this wave
    const ushort_t* k_lds = smem[j & 1];
    const ushort_t* v_lds = smem[j & 1] + 4096;

    // S^T[kk=kkb*16+quad*4+r][q=l16] per group
    floatx4 sacc[2][4];
#pragma unroll
    for (int kkb = 0; kkb < 4; ++kkb) {
      const ushort_t* krow = k_lds + (kkb * 16 + l16) * 64;
      shortx8 af0 = *(const shortx8*)(krow + (quad ^ (l16 & 7)) * 8);
      shortx8 af1 = *(const shortx8*)(krow + ((4 | quad) ^ (l16 & 7)) * 8);
#pragma unroll
      for (int grp = 0; grp < 2; ++grp) {
        floatx4 acc = {0.f, 0.f, 0.f, 0.f};
        acc = __builtin_amdgcn_mfma_f32_16x16x32_bf16(af0, qf[grp][0], acc, 0, 0, 0);
        acc = __builtin_amdgcn_mfma_f32_16x16x32_bf16(af1, qf[grp][1], acc, 0, 0, 0);
        sacc[grp][kkb] = acc;
      }
    }
    // diagonal masking (global indices)
#pragma unroll
    for (int grp = 0; grp < 2; ++grp) {
      const int qg = q0 + wave * 32 + grp * 16 + l16;
      if ((j << 6) + 63 > q0 + wave * 32 + grp * 16) {
#pragma unroll
        for (int kkb = 0; kkb < 4; ++kkb)
#pragma unroll
          for (int r = 0; r < 4; ++r)
            if ((j << 6) + kkb * 16 + quad * 4 + r > qg) sacc[grp][kkb][r] = -3.0e38f;
      }
    }

    // no-max softmax: p = exp2(s); per-lane partial l
    shortx4 pf[2][4];
#pragma unroll
    for (int grp = 0; grp < 2; ++grp) {
      float psum = 0.f;
#pragma unroll
      for (int kkb = 0; kkb < 4; ++kkb) {
        float p0 = fast_exp2(sacc[grp][kkb][0]);
        float p1 = fast_exp2(sacc[grp][kkb][1]);
        float p2 = fast_exp2(sacc[grp][kkb][2]);
        float p3 = fast_exp2(sacc[grp][kkb][3]);
        psum += (p0 + p1) + (p2 + p3);
        pf[grp][kkb] = mk_sx4(pack2bf(p0, p1), pack2bf(p2, p3));
      }
      l_run[grp] += psum;
    }

    // PV: oacc[grp][db] += V^T[d=db*16+..][kk block] * P^T
#pragma unroll
    for (int kkb = 0; kkb < 4; ++kkb) {
      const int jj = ((2 * kkb + (quad >> 1)) ^ (l16 & 7)) * 8 + (quad & 1) * 4;
#pragma unroll
      for (int db = 0; db < 4; ++db) {
        shortx4 vf = *(const shortx4*)(v_lds + (db * 16 + l16) * 64 + jj);
        oacc[0][db] = mfma16x16x16bf16(vf, pf[0][kkb], oacc[0][db]);
        oacc[1][db] = mfma16x16x16bf16(vf, pf[1][kkb], oacc[1][db]);
      }
    }
  }

  // epilogue: reduce l across quads, normalize, pack, transpose via LDS
  __syncthreads();
  ushort_t* sm = &smem[0][0];
#pragma unroll
  for (int grp = 0; grp < 2; ++grp) {
    float l0 = l_run[grp];
    l0 += __shfl_xor(l0, 16);
    l0 += __shfl_xor(l0, 32);
    float inv_l = 1.0f / l0;
    int row = wave * 32 + grp * 16 + l16;
#pragma unroll
    for (int db = 0; db < 4; ++db) {
#pragma unroll
      for (int rr = 0; rr < 2; ++rr) {
        unsigned pk = pack2bf(oacc[grp][db][rr * 2] * inv_l, oacc[grp][db][rr * 2 + 1] * inv_l);
        *(unsigned*)(sm + row * 72 + db * 16 + quad * 4 + rr * 2) = pk;
      }
    }
  }
  __syncthreads();
  {
    int r = tid >> 1, c = (tid & 1) * 32;
    const ushort_t* src = sm + r * 72 + c;
    ushort_t* dst = O + ((size_t)b * S_ + q0 + r) * D_ + hoff + c;
    uint4 v0 = *(const uint4*)(src);
    uint4 v1 = *(const uint4*)(src + 8);
    uint4 v2 = *(const uint4*)(src + 16);
    uint4 v3 = *(const uint4*)(src + 24);
    *(uint4*)(dst) = v0;
    *(uint4*)(dst + 8) = v1;
    *(uint4*)(dst + 16) = v2;
    *(uint4*)(dst + 24) = v3;
  }
}

// ---------------------------------------------------------------------------
extern "C" void kernel_launch(void* const* d_in, const int* in_sizes, int n_in,
                              void* d_out, int out_size, void* d_ws, size_t ws_size,
                              hipStream_t stream) {
  (void)in_sizes; (void)n_in; (void)out_size; (void)ws_size;
  char* ws = (char*)d_ws;
  ushort_t* O  = (ushort_t*)(ws + 0);          // attention output (8 MB)
  ushort_t* wq = (ushort_t*)(ws + 25165824);
  ushort_t* wk = (ushort_t*)(ws + 27262976);
  ushort_t* wv = (ushort_t*)(ws + 29360128);
  ushort_t* wo = (ushort_t*)(ws + 31457280);
  ushort_t* Qp = (ushort_t*)(ws + 33554432);
  ushort_t* Kp = (ushort_t*)(ws + 41943040);
  ushort_t* Vt = (ushort_t*)(ws + 50331648);  // V GEMM writes transposed here

  ConvWArgs cw;
  cw.src[0] = (const float*)d_in[4];  cw.dst[0] = wq;
  cw.src[1] = (const float*)d_in[6];  cw.dst[1] = wk;
  cw.src[2] = (const float*)d_in[8];  cw.dst[2] = wv;
  cw.src[3] = (const float*)d_in[10]; cw.dst[3] = wo;
  convert_w_kernel<<<dim3(1024), dim3(256), 0, stream>>>(cw);

  QkvArgs qa;
  qa.Af[0] = (const float*)d_in[0]; qa.W[0] = wq; qa.bias[0] = (const float*)d_in[5]; qa.out[0] = Qp;
  qa.Af[1] = (const float*)d_in[1]; qa.W[1] = wk; qa.bias[1] = (const float*)d_in[7]; qa.out[1] = Kp;
  qa.Af[2] = (const float*)d_in[2]; qa.W[2] = wv; qa.bias[2] = (const float*)d_in[9]; qa.out[2] = Vt;
  qa.scale[0] = 0.125f * 1.44269504089f;  // fold 1/sqrt(dk) * log2(e) into Q
  qa.scale[1] = 1.0f;
  qa.scale[2] = 1.0f;
  gemm_qkv_kernel<<<dim3(8, 32, 3), dim3(256), 0, stream>>>(qa);

  attn_kernel<<<dim3(512), dim3(256), 0, stream>>>(Qp, Kp, Vt, O);

  gemm_out_kernel<<<dim3(8, 64, 1), dim3(256), 0, stream>>>(
      O, wo, (const float*)d_in[11], (float*)d_out);
}

// Round 9
// 227.717 us; speedup vs baseline: 1.0560x; 1.0560x over previous
//
#include <hip/hip_runtime.h>
#include <hip/hip_bf16.h>
#include <stdint.h>

#define B_ 2
#define S_ 2048
#define D_ 1024
#define H_ 16
#define DK_ 64

typedef __attribute__((ext_vector_type(4))) float floatx4;
typedef __attribute__((ext_vector_type(8))) short shortx8;
typedef __attribute__((ext_vector_type(4))) short shortx4;
typedef unsigned short ushort_t;

// f32 -> bf16 round-to-nearest-even (used for GEMM outputs)
__device__ inline ushort_t f2bf(float f) {
  union { float f; unsigned u; } v; v.f = f;
  unsigned r = v.u + 0x7FFFu + ((v.u >> 16) & 1u);
  return (ushort_t)(r >> 16);
}

// pack two f32 -> bf16x2 by truncation (1 v_perm); fine for P >= 0 / O
__device__ inline unsigned pack2bf(float lo, float hi) {
  return __builtin_amdgcn_perm(__float_as_uint(hi), __float_as_uint(lo), 0x07060302u);
}

__device__ inline shortx4 mk_sx4(unsigned lo, unsigned hi) {
  union { unsigned u[2]; shortx4 s; } v; v.u[0] = lo; v.u[1] = hi; return v.s;
}

__device__ inline float fast_exp2(float x) {
#if __has_builtin(__builtin_amdgcn_exp2f)
  return __builtin_amdgcn_exp2f(x);
#else
  return __expf(0.69314718056f * x);
#endif
}

__device__ inline void gload_lds16(const void* g, void* l) {
  __builtin_amdgcn_global_load_lds(
      (const __attribute__((address_space(1))) unsigned int*)g,
      (__attribute__((address_space(3))) unsigned int*)l, 16, 0, 0);
}

__device__ inline floatx4 mfma16x16x16bf16(shortx4 a, shortx4 b, floatx4 c) {
#if __has_builtin(__builtin_amdgcn_mfma_f32_16x16x16bf16_1k)
  return __builtin_amdgcn_mfma_f32_16x16x16bf16_1k(a, b, c, 0, 0, 0);
#else
  floatx4 d;
  asm("v_mfma_f32_16x16x16_bf16 %0, %1, %2, %3" : "=v"(d) : "v"(a), "v"(b), "v"(c));
  return d;
#endif
}

// ---------------- fp32 -> bf16 conversion (7 tensors fused) ----------------
// NOTE (round 8 failure): fusing the activation conversion into the QKV GEMM
// via global->VGPR->pack->ds_write regressed 42->70 us: that path cannot use
// the async vmcnt queue, so every K-iter carried an exposed ~900-cyc load
// latency. Conversion stays standalone (pure-BW, ~23 us).
struct ConvArgs {
  const float* src[7];
  ushort_t* dst[7];
};

__global__ __launch_bounds__(256) void convert_kernel(ConvArgs a) {
  int blk = blockIdx.x;
  int seg, bis;
  if (blk < 3072) { seg = blk >> 10; bis = blk & 1023; }
  else { int bb = blk - 3072; seg = 3 + (bb >> 8); bis = bb & 255; }
  const float4* src = (const float4*)(a.src[seg]) + (size_t)bis * 1024;
  ushort4* dst = (ushort4*)(a.dst[seg]) + (size_t)bis * 1024;
#pragma unroll
  for (int i = 0; i < 4; ++i) {
    int idx = i * 256 + threadIdx.x;
    float4 v = src[idx];
    ushort4 o;
    o.x = f2bf(v.x); o.y = f2bf(v.y); o.z = f2bf(v.z); o.w = f2bf(v.w);
    dst[idx] = o;
  }
}

// ---------------- GEMM: C[m][n] = (sum_k A[m][k]*W[n][k] + bias[n])*scl ----
// TM x 128 tile, BK=32, double-buffered LDS with global_load_lds prefetch.
// 4 waves in 2x2 layout: wave tile (TM/2) x 64.
// outmode (RUNTIME arg -- one template instantiation => one LDS allocation;
// two instantiations in one kernel would DOUBLE the static LDS and halve
// occupancy, which cost 8 us in round 6):
//   0 = bf16 row-major, 1 = f32 row-major,
//   2 = bf16 V-transpose out[(b*1024+n)*2048 + s], m = b*2048+s.
template <int TM>
__device__ inline void gemm_bt_core(const ushort_t* __restrict__ A,
                                    const ushort_t* __restrict__ W,
                                    const float* __restrict__ bias,
                                    float scl,
                                    void* __restrict__ outp,
                                    int m0, int n0, int N, int K, int outmode) {
  constexpr int LDSU = (TM + 128) * 32;  // ushorts per buffer
  constexpr int GA = TM / 16;            // A gloads (16 rows each)
  constexpr int GW = (GA + 8) / 4;       // gloads per wave
  constexpr int MI = TM / 32;            // m-frags per wave
  __shared__ ushort_t smem[2][LDSU];
  const int tid = threadIdx.x;
  const int wave = tid >> 6;
  const int lane = tid & 63;
  const int quad = lane >> 4;
  const int l16 = lane & 15;
  const int wm = (wave >> 1) * (TM / 2);
  const int wn = (wave & 1) * 64;

  floatx4 acc[MI][4] = {};

  // staging: gload g covers 16 rows; lane -> row lane>>2, col (lane&3)*8
  const ushort_t* gsrc[GW];
  int ldst[GW];
#pragma unroll
  for (int i = 0; i < GW; ++i) {
    int g = wave * GW + i;
    int row = lane >> 2;
    int col = (lane & 3) * 8;
    if (g < GA) {
      gsrc[i] = A + (size_t)(m0 + g * 16 + row) * K + col;
      ldst[i] = g * 512;
    } else {
      gsrc[i] = W + (size_t)(n0 + (g - GA) * 16 + row) * K + col;
      ldst[i] = TM * 32 + (g - GA) * 512;
    }
  }

#pragma unroll
  for (int i = 0; i < GW; ++i) gload_lds16(gsrc[i], &smem[0][ldst[i]]);

  const int niter = K >> 5;
  for (int j = 0; j < niter; ++j) {
    __syncthreads();
    if (j + 1 < niter) {
      const int ko = (j + 1) * 32;
      ushort_t* bufn = smem[(j + 1) & 1];
#pragma unroll
      for (int i = 0; i < GW; ++i) gload_lds16(gsrc[i] + ko, bufn + ldst[i]);
    }
    const ushort_t* aT = smem[j & 1];
    const ushort_t* bT = smem[j & 1] + TM * 32;
    shortx8 af[MI], bf[4];
#pragma unroll
    for (int mi = 0; mi < MI; ++mi)
      af[mi] = *(const shortx8*)(aT + (wm + mi * 16 + l16) * 32 + quad * 8);
#pragma unroll
    for (int ni = 0; ni < 4; ++ni)
      bf[ni] = *(const shortx8*)(bT + (wn + ni * 16 + l16) * 32 + quad * 8);
#pragma unroll
    for (int mi = 0; mi < MI; ++mi)
#pragma unroll
      for (int ni = 0; ni < 4; ++ni)
        acc[mi][ni] = __builtin_amdgcn_mfma_f32_16x16x32_bf16(af[mi], bf[ni], acc[mi][ni], 0, 0, 0);
  }

  // epilogue: C/D layout col=lane&15, row=quad*4+r
#pragma unroll
  for (int ni = 0; ni < 4; ++ni) {
    int n = n0 + wn + ni * 16 + l16;
    float bv = bias[n];
#pragma unroll
    for (int mi = 0; mi < MI; ++mi) {
      if (outmode == 2) {
        int m = m0 + wm + mi * 16 + quad * 4;
        int b = m >> 11, s = m & 2047;
        ushort_t* dst = (ushort_t*)outp + (((size_t)(b * 1024 + n)) << 11) + s;
        uint2 pk;
        pk.x = (unsigned)f2bf(acc[mi][ni][0] + bv) |
               ((unsigned)f2bf(acc[mi][ni][1] + bv) << 16);
        pk.y = (unsigned)f2bf(acc[mi][ni][2] + bv) |
               ((unsigned)f2bf(acc[mi][ni][3] + bv) << 16);
        *(uint2*)(dst) = pk;  // single 8B store (8B-aligned: s = quad*4)
      } else {
#pragma unroll
        for (int r = 0; r < 4; ++r) {
          int m = m0 + wm + mi * 16 + quad * 4 + r;
          float v = (acc[mi][ni][r] + bv) * scl;
          if (outmode == 1) ((float*)outp)[(size_t)m * N + n] = v;
          else ((ushort_t*)outp)[(size_t)m * N + n] = f2bf(v);
        }
      }
    }
  }
}

struct QkvArgs {
  const ushort_t* A[3];
  const ushort_t* W[3];
  const float* bias[3];
  ushort_t* out[3];
  float scale[3];
};

// grid (8,32,3); XCD swizzle: flat%8 == blockIdx.x -> make x the m-group so
// XCD c's L2 working set = 4 A-tiles (1MB) + full W (2MB) < 4MB.
// z==2 (V) writes the transposed layout consumed by attention (fused vtrans).
__global__ __launch_bounds__(256) void gemm_qkv_kernel(QkvArgs a) {
  int z = blockIdx.z;
  int m0 = (blockIdx.x * 4 + (blockIdx.y >> 3)) * 128;
  int n0 = (blockIdx.y & 7) * 128;
  gemm_bt_core<128>(a.A[z], a.W[z], a.bias[z], a.scale[z], a.out[z],
                    m0, n0, D_, D_, z == 2 ? 2 : 0);
}

// grid (8,64); 64x128 tiles (2 blocks/CU), same swizzle principle.
__global__ __launch_bounds__(256) void gemm_out_kernel(const ushort_t* __restrict__ A,
                                                       const ushort_t* __restrict__ W,
                                                       const float* __restrict__ bias,
                                                       float* __restrict__ out) {
  int m0 = (blockIdx.x * 8 + (blockIdx.y >> 3)) * 64;
  int n0 = (blockIdx.y & 7) * 128;
  gemm_bt_core<64>(A, W, bias, 1.0f, out, m0, n0, D_, D_, 1);
}

// ---------------- flash attention (causal), pipelined, no-max softmax ------
// 1D grid of 512; id<256 -> (b=0, qt=15-(id>>4)), id>=256 -> (b=1, qt=id>>4).
// With round-robin block->CU dispatch, CU c gets blocks c and c+256 whose
// k-tile counts sum to a CONSTANT 17 -> balanced makespan.
// Round 9: K-tile 128 (two 64-k compute halves per barrier) -- halves the
// per-iteration barrier+vmcnt-drain count (36 -> 17-18 per CU pair), which
// rounds 2-3 identified as the dominant exposed cost. LDS 2 x 32 KB = 64 KB
// -> still 2 blocks/CU.
__global__ __launch_bounds__(256, 2) void attn_kernel(const ushort_t* __restrict__ Qp,
                                                      const ushort_t* __restrict__ Kp,
                                                      const ushort_t* __restrict__ Vt,
                                                      ushort_t* __restrict__ O) {
  const int id = blockIdx.x;
  const int h = id & 15;
  const int qq = (id & 255) >> 4;
  const int b = id >> 8;
  const int qt = b ? qq : 15 - qq;
  const int q0 = qt * 128;
  const int tid = threadIdx.x;
  const int wave = tid >> 6;
  const int lane = tid & 63;
  const int quad = lane >> 4;
  const int l16 = lane & 15;

  __shared__ ushort_t smem[2][16384];  // per buf: K[128][64] | V^T[64][128]

  const size_t hoff = (size_t)h * DK_;

  // Q B-frags: lane holds Q[q=l16][d=ks*32+quad*8+i] (already exp2-scaled)
  shortx8 qf[2][2];
#pragma unroll
  for (int grp = 0; grp < 2; ++grp) {
    const ushort_t* qrow = Qp + ((size_t)b * S_ + q0 + wave * 32 + grp * 16 + l16) * D_ + hoff;
#pragma unroll
    for (int ks = 0; ks < 2; ++ks)
      qf[grp][ks] = *(const shortx8*)(qrow + ks * 32 + quad * 8);
  }

  // K staging: wave stages rows [wave*32, +32) of the 128-row K tile via 4
  // gloads (8 rows each); XOR-swizzle: stored chunk pos (lane&7) holds global
  // chunk (lane&7)^r8 of row r8.
  const int r8 = lane >> 3;
  const int jj8 = ((lane & 7) ^ r8) * 8;
  const ushort_t* kb[4];
#pragma unroll
  for (int g = 0; g < 4; ++g) {
    int r = wave * 32 + g * 8 + r8;
    kb[g] = Kp + ((size_t)b * S_ + r) * D_ + hoff + jj8;
  }
  // V^T staging: wave stages d-rows [wave*16, +16) x 128 kk via 4 gloads
  // (4 rows x 16 chunks each); stored chunk pos c holds global chunk
  // c ^ (row&15)  (16-chunk rows -> 4-bit xor).
  const int r4 = lane >> 4;
  const ushort_t* vb[4];
#pragma unroll
  for (int g = 0; g < 4; ++g) {
    int r = wave * 16 + g * 4 + r4;
    int cpos = ((lane & 15) ^ ((g * 4 + r4) & 15)) * 8;
    vb[g] = Vt + ((size_t)(b * H_ + h) * 64 + r) * S_ + cpos;
  }

  floatx4 oacc[2][4] = {};
  float l_run[2] = {0.f, 0.f};
  const int nj = qt + 1;
  const int qwave_max = q0 + wave * 32 + 31;

  // preload tile 0 into buffer 0
#pragma unroll
  for (int g = 0; g < 4; ++g) {
    gload_lds16(kb[g], &smem[0][wave * 2048 + g * 512]);
    gload_lds16(vb[g], &smem[0][8192 + wave * 2048 + g * 512]);
  }

  for (int j = 0; j < nj; ++j) {
    __syncthreads();
    if (j + 1 < nj) {
      ushort_t* bufn = smem[(j + 1) & 1];
      const size_t ko = (size_t)(j + 1) * 128 * D_;
      const int vo = (j + 1) * 128;
#pragma unroll
      for (int g = 0; g < 4; ++g) {
        gload_lds16(kb[g] + ko, bufn + wave * 2048 + g * 512);
        gload_lds16(vb[g] + vo, bufn + 8192 + wave * 2048 + g * 512);
      }
    }
    if (j * 128 > qwave_max) continue;  // whole tile masked for this wave
    const ushort_t* k_lds = smem[j & 1];
    const ushort_t* v_lds = smem[j & 1] + 8192;

#pragma unroll
    for (int half = 0; half < 2; ++half) {
      const int kbase = j * 128 + half * 64;
      if (kbase > qwave_max) break;  // upper half masked

      // S^T[kk=kbase+kkb*16+quad*4+r][q=l16] per group
      floatx4 sacc[2][4];
#pragma unroll
      for (int kkb = 0; kkb < 4; ++kkb) {
        const ushort_t* krow = k_lds + (half * 64 + kkb * 16 + l16) * 64;
        shortx8 af0 = *(const shortx8*)(krow + (quad ^ (l16 & 7)) * 8);
        shortx8 af1 = *(const shortx8*)(krow + ((4 | quad) ^ (l16 & 7)) * 8);
#pragma unroll
        for (int grp = 0; grp < 2; ++grp) {
          floatx4 acc = {0.f, 0.f, 0.f, 0.f};
          acc = __builtin_amdgcn_mfma_f32_16x16x32_bf16(af0, qf[grp][0], acc, 0, 0, 0);
          acc = __builtin_amdgcn_mfma_f32_16x16x32_bf16(af1, qf[grp][1], acc, 0, 0, 0);
          sacc[grp][kkb] = acc;
        }
      }
      // diagonal masking (global indices)
#pragma unroll
      for (int grp = 0; grp < 2; ++grp) {
        const int qg = q0 + wave * 32 + grp * 16 + l16;
        if (kbase + 63 > q0 + wave * 32 + grp * 16) {
#pragma unroll
          for (int kkb = 0; kkb < 4; ++kkb)
#pragma unroll
            for (int r = 0; r < 4; ++r)
              if (kbase + kkb * 16 + quad * 4 + r > qg) sacc[grp][kkb][r] = -3.0e38f;
        }
      }

      // no-max softmax: p = exp2(s); per-lane partial l
      shortx4 pf[2][4];
#pragma unroll
      for (int grp = 0; grp < 2; ++grp) {
        float psum = 0.f;
#pragma unroll
        for (int kkb = 0; kkb < 4; ++kkb) {
          float p0 = fast_exp2(sacc[grp][kkb][0]);
          float p1 = fast_exp2(sacc[grp][kkb][1]);
          float p2 = fast_exp2(sacc[grp][kkb][2]);
          float p3 = fast_exp2(sacc[grp][kkb][3]);
          psum += (p0 + p1) + (p2 + p3);
          pf[grp][kkb] = mk_sx4(pack2bf(p0, p1), pack2bf(p2, p3));
        }
        l_run[grp] += psum;
      }

      // PV: oacc[grp][db] += V^T[d=db*16+l16][kk block] * P^T
#pragma unroll
      for (int kkb = 0; kkb < 4; ++kkb) {
        const int jj = ((half * 8 + kkb * 2 + (quad >> 1)) ^ l16) * 8 + (quad & 1) * 4;
#pragma unroll
        for (int db = 0; db < 4; ++db) {
          shortx4 vf = *(const shortx4*)(v_lds + (db * 16 + l16) * 128 + jj);
          oacc[0][db] = mfma16x16x16bf16(vf, pf[0][kkb], oacc[0][db]);
          oacc[1][db] = mfma16x16x16bf16(vf, pf[1][kkb], oacc[1][db]);
        }
      }
    }
  }

  // epilogue: reduce l across quads, normalize, pack, transpose via LDS
  __syncthreads();
  ushort_t* sm = &smem[0][0];
#pragma unroll
  for (int grp = 0; grp < 2; ++grp) {
    float l0 = l_run[grp];
    l0 += __shfl_xor(l0, 16);
    l0 += __shfl_xor(l0, 32);
    float inv_l = 1.0f / l0;
    int row = wave * 32 + grp * 16 + l16;
#pragma unroll
    for (int db = 0; db < 4; ++db) {
#pragma unroll
      for (int rr = 0; rr < 2; ++rr) {
        unsigned pk = pack2bf(oacc[grp][db][rr * 2] * inv_l, oacc[grp][db][rr * 2 + 1] * inv_l);
        *(unsigned*)(sm + row * 72 + db * 16 + quad * 4 + rr * 2) = pk;
      }
    }
  }
  __syncthreads();
  {
    int r = tid >> 1, c = (tid & 1) * 32;
    const ushort_t* src = sm + r * 72 + c;
    ushort_t* dst = O + ((size_t)b * S_ + q0 + r) * D_ + hoff + c;
    uint4 v0 = *(const uint4*)(src);
    uint4 v1 = *(const uint4*)(src + 8);
    uint4 v2 = *(const uint4*)(src + 16);
    uint4 v3 = *(const uint4*)(src + 24);
    *(uint4*)(dst) = v0;
    *(uint4*)(dst + 8) = v1;
    *(uint4*)(dst + 16) = v2;
    *(uint4*)(dst + 24) = v3;
  }
}

// ---------------------------------------------------------------------------
extern "C" void kernel_launch(void* const* d_in, const int* in_sizes, int n_in,
                              void* d_out, int out_size, void* d_ws, size_t ws_size,
                              hipStream_t stream) {
  (void)in_sizes; (void)n_in; (void)out_size; (void)ws_size;
  char* ws = (char*)d_ws;
  ushort_t* xq = (ushort_t*)(ws + 0);
  ushort_t* xk = (ushort_t*)(ws + 8388608);
  ushort_t* xv = (ushort_t*)(ws + 16777216);
  ushort_t* wq = (ushort_t*)(ws + 25165824);
  ushort_t* wk = (ushort_t*)(ws + 27262976);
  ushort_t* wv = (ushort_t*)(ws + 29360128);
  ushort_t* wo = (ushort_t*)(ws + 31457280);
  ushort_t* Qp = (ushort_t*)(ws + 33554432);
  ushort_t* Kp = (ushort_t*)(ws + 41943040);
  ushort_t* Vt = (ushort_t*)(ws + 50331648);  // V GEMM writes transposed here
  ushort_t* O = xq;   // xq dead after QKV GEMM

  ConvArgs ca;
  ca.src[0] = (const float*)d_in[0];  ca.dst[0] = xq;
  ca.src[1] = (const float*)d_in[1];  ca.dst[1] = xk;
  ca.src[2] = (const float*)d_in[2];  ca.dst[2] = xv;
  ca.src[3] = (const float*)d_in[4];  ca.dst[3] = wq;
  ca.src[4] = (const float*)d_in[6];  ca.dst[4] = wk;
  ca.src[5] = (const float*)d_in[8];  ca.dst[5] = wv;
  ca.src[6] = (const float*)d_in[10]; ca.dst[6] = wo;
  convert_kernel<<<dim3(4096), dim3(256), 0, stream>>>(ca);

  QkvArgs qa;
  qa.A[0] = xq; qa.W[0] = wq; qa.bias[0] = (const float*)d_in[5]; qa.out[0] = Qp;
  qa.A[1] = xk; qa.W[1] = wk; qa.bias[1] = (const float*)d_in[7]; qa.out[1] = Kp;
  qa.A[2] = xv; qa.W[2] = wv; qa.bias[2] = (const float*)d_in[9]; qa.out[2] = Vt;
  qa.scale[0] = 0.125f * 1.44269504089f;  // fold 1/sqrt(dk) * log2(e) into Q
  qa.scale[1] = 1.0f;
  qa.scale[2] = 1.0f;
  gemm_qkv_kernel<<<dim3(8, 32, 3), dim3(256), 0, stream>>>(qa);

  attn_kernel<<<dim3(512), dim3(256), 0, stream>>>(Qp, Kp, Vt, O);

  gemm_out_kernel<<<dim3(8, 64, 1), dim3(256), 0, stream>>>(
      O, wo, (const float*)d_in[11], (float*)d_out);
}